// Round 3
// baseline (104.662 us; speedup 1.0000x reference)
//
#include <hip/hip_runtime.h>
#include <math.h>

#define D_DIM 256
#define TILE  256
#define BK    64   // k-elems per stage step (128 B per row)

typedef __attribute__((ext_vector_type(8)))  short short8v;
typedef __attribute__((ext_vector_type(16))) float f32x16;

#define AS_GLOBAL(p) ((const __attribute__((address_space(1))) void*)(p))
#define AS_LDS(p)    ((__attribute__((address_space(3))) void*)(p))

// RNE float -> bf16 (finite inputs)
__device__ __forceinline__ unsigned short f2bf(float f) {
    unsigned int u = __float_as_uint(f);
    unsigned int r = (u + 0x7fffu + ((u >> 16) & 1u)) >> 16;
    return (unsigned short)r;
}

// ---------------------------------------------------------------------------
// Kernel A: per-wave row normalize (validated round 2). Block=256 (4 waves),
// wave w -> row i = blockIdx.x*4+w. float4 loads, shuffle-only reductions.
__global__ __launch_bounds__(256) void normalize_kernel(
        const float* __restrict__ A, const float* __restrict__ Bm,
        unsigned short* __restrict__ Xb, float* __restrict__ SQ,
        float* __restrict__ partials, int B_rows) {
    __shared__ float red[4];
    int lane = threadIdx.x & 63;
    int w    = threadIdx.x >> 6;
    int i    = blockIdx.x * 4 + w;

    const float4* A4 = (const float4*)(A + (size_t)i * D_DIM);
    const float4* B4 = (const float4*)(Bm + (size_t)i * D_DIM);
    float4 av = A4[lane];
    float4 bv = B4[lane];

    float sa = av.x*av.x + av.y*av.y + av.z*av.z + av.w*av.w;
    float sb = bv.x*bv.x + bv.y*bv.y + bv.z*bv.z + bv.w*bv.w;
    #pragma unroll
    for (int off = 32; off > 0; off >>= 1) {
        sa += __shfl_xor(sa, off, 64);
        sb += __shfl_xor(sb, off, 64);
    }
    float dena = fmaxf(sqrtf(sa), 1e-12f);
    float denb = fmaxf(sqrtf(sb), 1e-12f);
    float ia = 1.0f / dena, ib = 1.0f / denb;

    float4 an = {av.x*ia, av.y*ia, av.z*ia, av.w*ia};
    float4 bn = {bv.x*ib, bv.y*ib, bv.z*ib, bv.w*ib};

    ushort4 ua = {f2bf(an.x), f2bf(an.y), f2bf(an.z), f2bf(an.w)};
    ushort4 ub = {f2bf(bn.x), f2bf(bn.y), f2bf(bn.z), f2bf(bn.w)};
    ((ushort4*)(Xb + (size_t)i * D_DIM))[lane]            = ua;
    ((ushort4*)(Xb + (size_t)(B_rows + i) * D_DIM))[lane] = ub;

    float dx = an.x-bn.x, dy = an.y-bn.y, dz = an.z-bn.z, dw = an.w-bn.w;
    float sd = dx*dx + dy*dy + dz*dz + dw*dw;
    #pragma unroll
    for (int off = 32; off > 0; off >>= 1) sd += __shfl_down(sd, off, 64);

    if (lane == 0) {
        SQ[i]          = sa * ia * ia;
        SQ[B_rows + i] = sb * ib * ib;
        red[w] = sd;
    }
    __syncthreads();
    if (threadIdx.x == 0)
        atomicAdd(&partials[blockIdx.x & 63], red[0]+red[1]+red[2]+red[3]);
}

// ---------------------------------------------------------------------------
// Kernel B: uniformity via bf16 MFMA Gram. 256x256 tile, 8 waves (4x2 grid,
// wave-tile 64x128), BK=64 double-buffered, T3-min pipeline: stage-next
// issued before compute, vmcnt(0) after compute, raw s_barrier (no drain).
// Both-sides XOR swizzle (linear LDS dest via global_load_lds(16B),
// inverse-swizzled global source, swizzled ds_read_b128) — validated round 2.
__device__ __forceinline__ short8v frag_read(const unsigned short* base, int r, int kb) {
    int off = r * 128 + (kb ^ ((r & 7) << 4));
    return *reinterpret_cast<const short8v*>(reinterpret_cast<const char*>(base) + off);
}

__global__ __launch_bounds__(512, 2) void uniform_mfma_kernel(
        const unsigned short* __restrict__ Xb, const float* __restrict__ SQ,
        float* __restrict__ partials, int n_panels) {
    __shared__ __align__(16) unsigned short As[2][TILE * BK];  // 2 x 32 KB
    __shared__ __align__(16) unsigned short Bs[2][TILE * BK];  // 2 x 32 KB
    __shared__ float sqa[TILE], sqb[TILE], red[8];

    int t    = threadIdx.x;
    int lane = t & 63;
    int w    = t >> 6;       // 0..7
    int wr   = w >> 1;       // 0..3 -> i offset wr*64
    int wc   = w & 1;        // 0..1 -> j offset wc*128

    // decode (ib, jb) with jb >= ib from linear block id (<= 32 scalar iters)
    int rem = blockIdx.x;
    int ib  = 0;
    while (rem >= n_panels - ib) { rem -= n_panels - ib; ++ib; }
    int jb = ib + rem;

    int rowA0 = ib * TILE, rowB0 = jb * TILE;
    if (t < TILE) sqa[t]        = SQ[rowA0 + t];
    else          sqb[t - TILE] = SQ[rowB0 + t - TILE];

    // Stage one BK-slice of A and B tiles into buffer `bi`.
    // Per it: 8 waves x 8 rows = 64 rows; 8 lanes x 16B per row (BK=128B).
    // Source chunk is inverse-swizzled so linear LDS + swizzled read match.
#define STAGE(bi, k0)                                                         \
    do {                                                                      \
        _Pragma("unroll")                                                     \
        for (int it = 0; it < 4; ++it) {                                      \
            int row   = w * 32 + it * 8 + (lane >> 3);                        \
            int chunk = ((lane & 7) ^ ((lane >> 3) & 7)) << 3;                \
            const unsigned short* sA = Xb + (size_t)(rowA0 + row) * D_DIM + (k0) + chunk; \
            const unsigned short* sB = Xb + (size_t)(rowB0 + row) * D_DIM + (k0) + chunk; \
            unsigned short* dA = &As[bi][(w * 32 + it * 8) * BK];             \
            unsigned short* dB = &Bs[bi][(w * 32 + it * 8) * BK];             \
            __builtin_amdgcn_global_load_lds(AS_GLOBAL(sA), AS_LDS(dA), 16, 0, 0); \
            __builtin_amdgcn_global_load_lds(AS_GLOBAL(sB), AS_LDS(dB), 16, 0, 0); \
        }                                                                     \
    } while (0)

    f32x16 acc[2][4] = {};

    int r_a0 = wr * 64 + (lane & 31), r_a1 = r_a0 + 32;
    int r_b0 = wc * 128 + (lane & 31);
    int r_b1 = r_b0 + 32, r_b2 = r_b0 + 64, r_b3 = r_b0 + 96;

#define COMPUTE(bi)                                                           \
    do {                                                                      \
        _Pragma("unroll")                                                     \
        for (int kk = 0; kk < 4; ++kk) {                                      \
            int kb = kk * 32 + ((lane >> 5) << 4);                            \
            short8v a0 = frag_read(&As[bi][0], r_a0, kb);                     \
            short8v a1 = frag_read(&As[bi][0], r_a1, kb);                     \
            short8v b0 = frag_read(&Bs[bi][0], r_b0, kb);                     \
            short8v b1 = frag_read(&Bs[bi][0], r_b1, kb);                     \
            short8v b2 = frag_read(&Bs[bi][0], r_b2, kb);                     \
            short8v b3 = frag_read(&Bs[bi][0], r_b3, kb);                     \
            acc[0][0] = __builtin_amdgcn_mfma_f32_32x32x16_bf16(a0, b0, acc[0][0], 0, 0, 0); \
            acc[0][1] = __builtin_amdgcn_mfma_f32_32x32x16_bf16(a0, b1, acc[0][1], 0, 0, 0); \
            acc[0][2] = __builtin_amdgcn_mfma_f32_32x32x16_bf16(a0, b2, acc[0][2], 0, 0, 0); \
            acc[0][3] = __builtin_amdgcn_mfma_f32_32x32x16_bf16(a0, b3, acc[0][3], 0, 0, 0); \
            acc[1][0] = __builtin_amdgcn_mfma_f32_32x32x16_bf16(a1, b0, acc[1][0], 0, 0, 0); \
            acc[1][1] = __builtin_amdgcn_mfma_f32_32x32x16_bf16(a1, b1, acc[1][1], 0, 0, 0); \
            acc[1][2] = __builtin_amdgcn_mfma_f32_32x32x16_bf16(a1, b2, acc[1][2], 0, 0, 0); \
            acc[1][3] = __builtin_amdgcn_mfma_f32_32x32x16_bf16(a1, b3, acc[1][3], 0, 0, 0); \
        }                                                                     \
    } while (0)

#define PIPE_FENCE()                                                          \
    do {                                                                      \
        asm volatile("s_waitcnt vmcnt(0)" ::: "memory");                      \
        __builtin_amdgcn_s_barrier();                                         \
        __builtin_amdgcn_sched_barrier(0);                                    \
    } while (0)

    // prologue
    STAGE(0, 0);
    asm volatile("s_waitcnt vmcnt(0)" ::: "memory");
    __syncthreads();  // also covers sqa/sqb LDS writes

    // K-steps: stage next, compute current, fence (stage latency hides
    // under the 32-MFMA cluster; never two buffers in flight at a read).
    STAGE(1, 64);
    COMPUTE(0);
    PIPE_FENCE();

    STAGE(0, 128);
    COMPUTE(1);
    PIPE_FENCE();

    STAGE(1, 192);
    COMPUTE(0);
    PIPE_FENCE();

    COMPUTE(1);

    // Epilogue: e = exp(-2 * max(sq_i + sq_j - 2*dot, 0)), reduce.
    // C layout (32x32): col = lane&31, row = (reg&3) + 8*(reg>>2) + 4*(lane>>5)
    float s   = 0.0f;
    int   col = lane & 31;
    int   rhi = (lane >> 5) * 4;
    #pragma unroll
    for (int si = 0; si < 2; ++si)
        #pragma unroll
        for (int sj = 0; sj < 4; ++sj)
            #pragma unroll
            for (int reg = 0; reg < 16; ++reg) {
                int il = wr * 64 + si * 32 + (reg & 3) + 8 * (reg >> 2) + rhi;
                int jl = wc * 128 + sj * 32 + col;
                float d2 = fmaxf(sqa[il] + sqb[jl] - 2.0f * acc[si][sj][reg], 0.0f);
                s += __expf(-2.0f * d2);
            }
    if (ib != jb) s *= 2.0f;

    #pragma unroll
    for (int off = 32; off > 0; off >>= 1) s += __shfl_down(s, off, 64);
    if (lane == 0) red[w] = s;
    __syncthreads();
    if (t == 0) {
        float tot = red[0]+red[1]+red[2]+red[3]+red[4]+red[5]+red[6]+red[7];
        atomicAdd(&partials[64 + (blockIdx.x & 63)], tot);
    }
#undef STAGE
#undef COMPUTE
#undef PIPE_FENCE
}

// ---------------------------------------------------------------------------
__global__ void finalize_kernel(const float* __restrict__ partials,
                                float* __restrict__ out, int B_rows) {
    int t = threadIdx.x;  // 64 threads
    float al = partials[t];
    float un = partials[64 + t];
    #pragma unroll
    for (int off = 32; off > 0; off >>= 1) {
        al += __shfl_down(al, off, 64);
        un += __shfl_down(un, off, 64);
    }
    if (t == 0) {
        float n = (float)(2 * B_rows);
        out[0] = al / (float)B_rows + (un - n) / (n * (n - 1.0f));
    }
}

// ---------------------------------------------------------------------------
extern "C" void kernel_launch(void* const* d_in, const int* in_sizes, int n_in,
                              void* d_out, int out_size, void* d_ws, size_t ws_size,
                              hipStream_t stream) {
    const float* A  = (const float*)d_in[0];
    const float* Bm = (const float*)d_in[1];
    float* out = (float*)d_out;

    int B_rows = in_sizes[0] / D_DIM;   // 4096
    int n_tot  = 2 * B_rows;            // 8192

    // ws layout: Xb (bf16 n*256 = 4 MB) | SQ (f32 n) | partials (f32 128)
    unsigned short* Xb = (unsigned short*)d_ws;
    float* SQ       = (float*)(Xb + (size_t)n_tot * D_DIM);
    float* partials = SQ + n_tot;

    hipMemsetAsync(partials, 0, 128 * sizeof(float), stream);

    normalize_kernel<<<B_rows / 4, 256, 0, stream>>>(A, Bm, Xb, SQ, partials, B_rows);

    int n_panels = n_tot / TILE;                    // 32
    int n_blocks = n_panels * (n_panels + 1) / 2;   // 528
    uniform_mfma_kernel<<<n_blocks, 512, 0, stream>>>(Xb, SQ, partials, n_panels);

    finalize_kernel<<<1, 64, 0, stream>>>(partials, out, B_rows);
}

// Round 4
// 88.358 us; speedup vs baseline: 1.1845x; 1.1845x over previous
//
#include <hip/hip_runtime.h>
#include <math.h>

#define D_DIM 256
#define TILE  128
#define BKE   64            // k-elements per stage step (128 B per row)
#define LDS_PAD 3072        // shorts of pad per buffer -> ~46 KB total -> 3 blocks/CU

typedef __attribute__((ext_vector_type(8))) short short8v;
typedef __attribute__((ext_vector_type(4))) float f32x4;

#define AS_GLOBAL(p) ((const __attribute__((address_space(1))) void*)(p))
#define AS_LDS(p)    ((__attribute__((address_space(3))) void*)(p))

// RNE float -> bf16 (finite inputs)
__device__ __forceinline__ unsigned short f2bf(float f) {
    unsigned int u = __float_as_uint(f);
    unsigned int r = (u + 0x7fffu + ((u >> 16) & 1u)) >> 16;
    return (unsigned short)r;
}

// ---------------------------------------------------------------------------
// Kernel A: per-wave row normalize (validated rounds 2-3). Block=256 (4
// waves), wave w -> row i = blockIdx.x*4+w. float4 loads, shuffle reductions.
// Each block writes its align partial to a UNIQUE slot (no atomics, no memset).
__global__ __launch_bounds__(256) void normalize_kernel(
        const float* __restrict__ A, const float* __restrict__ Bm,
        unsigned short* __restrict__ Xb, float* __restrict__ SQ,
        float* __restrict__ partials, int B_rows) {
    __shared__ float red[4];
    int lane = threadIdx.x & 63;
    int w    = threadIdx.x >> 6;
    int i    = blockIdx.x * 4 + w;

    const float4* A4 = (const float4*)(A + (size_t)i * D_DIM);
    const float4* B4 = (const float4*)(Bm + (size_t)i * D_DIM);
    float4 av = A4[lane];
    float4 bv = B4[lane];

    float sa = av.x*av.x + av.y*av.y + av.z*av.z + av.w*av.w;
    float sb = bv.x*bv.x + bv.y*bv.y + bv.z*bv.z + bv.w*bv.w;
    #pragma unroll
    for (int off = 32; off > 0; off >>= 1) {
        sa += __shfl_xor(sa, off, 64);
        sb += __shfl_xor(sb, off, 64);
    }
    float dena = fmaxf(sqrtf(sa), 1e-12f);
    float denb = fmaxf(sqrtf(sb), 1e-12f);
    float ia = 1.0f / dena, ib = 1.0f / denb;

    float4 an = {av.x*ia, av.y*ia, av.z*ia, av.w*ia};
    float4 bn = {bv.x*ib, bv.y*ib, bv.z*ib, bv.w*ib};

    ushort4 ua = {f2bf(an.x), f2bf(an.y), f2bf(an.z), f2bf(an.w)};
    ushort4 ub = {f2bf(bn.x), f2bf(bn.y), f2bf(bn.z), f2bf(bn.w)};
    ((ushort4*)(Xb + (size_t)i * D_DIM))[lane]            = ua;
    ((ushort4*)(Xb + (size_t)(B_rows + i) * D_DIM))[lane] = ub;

    float dx = an.x-bn.x, dy = an.y-bn.y, dz = an.z-bn.z, dw = an.w-bn.w;
    float sd = dx*dx + dy*dy + dz*dz + dw*dw;
    #pragma unroll
    for (int off = 32; off > 0; off >>= 1) sd += __shfl_down(sd, off, 64);

    if (lane == 0) {
        SQ[i]          = sa * ia * ia;
        SQ[B_rows + i] = sb * ib * ib;
        red[w] = sd;
    }
    __syncthreads();
    if (threadIdx.x == 0)
        partials[blockIdx.x] = red[0]+red[1]+red[2]+red[3];
}

// ---------------------------------------------------------------------------
// Kernel B: uniformity via bf16 MFMA Gram. m97-structure: 128x128 tile,
// 4 waves (2x2, wave-tile 64x64), 16x16x32 MFMA (reads/MFMA = 0.5), BK=64
// single-buffer 2-phase loop. Both-sides XOR swizzle (linear LDS dest via
// global_load_lds(16B), inverse-swizzled global source, swizzled
// ds_read_b128) — validated rounds 2-3. LDS padded to ~46 KB -> exactly
// 3 blocks/CU: 2080 blocks / 768 slots = 2.71 -> 90% sched efficiency.
__device__ __forceinline__ short8v frag_read(const short* base, int r, int kb) {
    int off = r * 128 + (kb ^ ((r & 7) << 4));   // bytes; row stride 128 B
    return *reinterpret_cast<const short8v*>(reinterpret_cast<const char*>(base) + off);
}

__global__ __launch_bounds__(256, 3) void uniform_mfma_kernel(
        const unsigned short* __restrict__ Xb, const float* __restrict__ SQ,
        float* __restrict__ partials, int n_panels) {
    __shared__ __align__(16) short As[TILE * BKE + LDS_PAD];  // 16 KB used + 6 KB pad
    __shared__ __align__(16) short Bs[TILE * BKE + LDS_PAD];
    __shared__ float sqa[TILE], sqb[TILE], red[4];

    int t    = threadIdx.x;
    int lane = t & 63;
    int w    = t >> 6;       // 0..3
    int wr   = w >> 1;       // A half: rows wr*64
    int wc   = w & 1;        // B half: rows wc*64

    // decode (ib, jb), jb >= ib, from linear block id
    int rem = blockIdx.x;
    int ib  = 0;
    while (rem >= n_panels - ib) { rem -= n_panels - ib; ++ib; }
    int jb = ib + rem;

    int rowA0 = ib * TILE, rowB0 = jb * TILE;
    if (t < TILE) sqa[t]        = SQ[rowA0 + t];
    else          sqb[t - TILE] = SQ[rowB0 + t - TILE];

    f32x4 acc[4][4] = {};

    for (int k0 = 0; k0 < D_DIM; k0 += BKE) {
        __syncthreads();   // previous-iter LDS reads done (covers sqa/sqb 1st iter)
        // STAGE: wave w stages rows [w*32, w*32+32) of both tiles.
        // lane -> row w*32+it*8+(l>>3), 16B slot (l&7); source granule
        // inverse-swizzled so linear LDS dest + swizzled read match.
        #pragma unroll
        for (int it = 0; it < 4; ++it) {
            int row  = w * 32 + it * 8 + (lane >> 3);
            int gel  = (((lane & 7) ^ (row & 7)) << 3);   // granule in elements
            const unsigned short* sA = Xb + (size_t)(rowA0 + row) * D_DIM + k0 + gel;
            const unsigned short* sB = Xb + (size_t)(rowB0 + row) * D_DIM + k0 + gel;
            short* dA = As + (w * 32 + it * 8) * BKE;
            short* dB = Bs + (w * 32 + it * 8) * BKE;
            __builtin_amdgcn_global_load_lds(AS_GLOBAL(sA), AS_LDS(dA), 16, 0, 0);
            __builtin_amdgcn_global_load_lds(AS_GLOBAL(sB), AS_LDS(dB), 16, 0, 0);
        }
        __syncthreads();   // staged data visible (compiler drains vmcnt)

        #pragma unroll
        for (int kk = 0; kk < 2; ++kk) {
            int kb = kk * 64 + ((lane >> 4) << 4);   // lane's 16B k-granule (bytes)
            short8v a[4], b[4];
            #pragma unroll
            for (int m = 0; m < 4; ++m)
                a[m] = frag_read(As, wr * 64 + m * 16 + (lane & 15), kb);
            #pragma unroll
            for (int n = 0; n < 4; ++n)
                b[n] = frag_read(Bs, wc * 64 + n * 16 + (lane & 15), kb);
            #pragma unroll
            for (int m = 0; m < 4; ++m)
                #pragma unroll
                for (int n = 0; n < 4; ++n)
                    acc[m][n] = __builtin_amdgcn_mfma_f32_16x16x32_bf16(
                        a[m], b[n], acc[m][n], 0, 0, 0);
        }
    }

    // Epilogue: e = exp(-2 * max(sq_i + sq_j - 2*dot, 0)), reduce.
    // C layout (16x16): col = lane&15, row = (lane>>4)*4 + reg  [m89]
    float s   = 0.0f;
    int   col = lane & 15;
    int   rhi = (lane >> 4) * 4;
    #pragma unroll
    for (int m = 0; m < 4; ++m)
        #pragma unroll
        for (int n = 0; n < 4; ++n)
            #pragma unroll
            for (int reg = 0; reg < 4; ++reg) {
                int il = wr * 64 + m * 16 + rhi + reg;
                int jl = wc * 64 + n * 16 + col;
                float d2 = fmaxf(sqa[il] + sqb[jl] - 2.0f * acc[m][n][reg], 0.0f);
                s += __expf(-2.0f * d2);
            }
    if (ib != jb) s *= 2.0f;

    #pragma unroll
    for (int off = 32; off > 0; off >>= 1) s += __shfl_down(s, off, 64);
    if (lane == 0) red[w] = s;
    __syncthreads();
    if (t == 0)
        partials[1024 + blockIdx.x] = red[0]+red[1]+red[2]+red[3];  // unique slot
}

// ---------------------------------------------------------------------------
// Finalize: sum 1024 align partials + n_blocks uniform partials, one block.
__global__ __launch_bounds__(256) void finalize_kernel(
        const float* __restrict__ partials, float* __restrict__ out,
        int B_rows, int n_blocks) {
    __shared__ float reda[4], redu[4];
    int t = threadIdx.x;
    float al = 0.0f, un = 0.0f;
    for (int i = t; i < 1024; i += 256)      al += partials[i];
    for (int i = t; i < n_blocks; i += 256)  un += partials[1024 + i];
    #pragma unroll
    for (int off = 32; off > 0; off >>= 1) {
        al += __shfl_down(al, off, 64);
        un += __shfl_down(un, off, 64);
    }
    if ((t & 63) == 0) { reda[t >> 6] = al; redu[t >> 6] = un; }
    __syncthreads();
    if (t == 0) {
        float sal = reda[0]+reda[1]+reda[2]+reda[3];
        float sun = redu[0]+redu[1]+redu[2]+redu[3];
        float n = (float)(2 * B_rows);
        out[0] = sal / (float)B_rows + (sun - n) / (n * (n - 1.0f));
    }
}

// ---------------------------------------------------------------------------
extern "C" void kernel_launch(void* const* d_in, const int* in_sizes, int n_in,
                              void* d_out, int out_size, void* d_ws, size_t ws_size,
                              hipStream_t stream) {
    const float* A  = (const float*)d_in[0];
    const float* Bm = (const float*)d_in[1];
    float* out = (float*)d_out;

    int B_rows = in_sizes[0] / D_DIM;   // 4096
    int n_tot  = 2 * B_rows;            // 8192

    // ws layout: Xb (bf16 n*256 = 4 MB) | SQ (f32 n) | partials (f32 1024+2080)
    unsigned short* Xb = (unsigned short*)d_ws;
    float* SQ       = (float*)(Xb + (size_t)n_tot * D_DIM);
    float* partials = SQ + n_tot;

    normalize_kernel<<<B_rows / 4, 256, 0, stream>>>(A, Bm, Xb, SQ, partials, B_rows);

    int n_panels = n_tot / TILE;                    // 64
    int n_blocks = n_panels * (n_panels + 1) / 2;   // 2080
    uniform_mfma_kernel<<<n_blocks, 256, 0, stream>>>(Xb, SQ, partials, n_panels);

    finalize_kernel<<<1, 256, 0, stream>>>(partials, out, B_rows, n_blocks);
}

// Round 5
// 83.810 us; speedup vs baseline: 1.2488x; 1.0543x over previous
//
#include <hip/hip_runtime.h>
#include <math.h>

#define D_DIM 256
#define TILE  128
#define BKE   128           // fp8 k-elements per K-step (128 B per LDS row)
#define LDS_BYTES (TILE * BKE)          // 16 KB per tile buffer
#define LDS_ALLOC (LDS_BYTES + 7168)    // pad -> ~48 KB/block total -> 3 blocks/CU

typedef __attribute__((ext_vector_type(4))) int   i32x4;
typedef __attribute__((ext_vector_type(8))) int   i32x8;
typedef __attribute__((ext_vector_type(4))) float f32x4;

#define AS_GLOBAL(p) ((const __attribute__((address_space(1))) void*)(p))
#define AS_LDS(p)    ((__attribute__((address_space(3))) void*)(p))

// ---------------------------------------------------------------------------
// f32 -> OCP e4m3fn (RNE). Inputs are unit-row elements, |x| <= 1.
// Linear (subnormal + first normal octaves) region a < 2^-5: code = rne(a*512).
// Normal region: rebias bit-trick with RNE at bit 20.
__device__ __forceinline__ unsigned int f2e4m3(float f) {
    unsigned int u = __float_as_uint(f);
    unsigned int s = (u >> 24) & 0x80u;
    float a = fabsf(f);
    unsigned int code;
    if (a < 0.03125f) {
        code = __float2uint_rn(a * 512.0f);        // 0..16, exact linear region
    } else {
        unsigned int x = u & 0x7fffffffu;
        unsigned int r = x - (120u << 23);         // rebias: exp-7 -> e4m3 exp
        r += 0x7ffffu + ((r >> 20) & 1u);          // RNE at bit 20
        code = r >> 20;
        if (code > 0x7eu) code = 0x7eu;            // paranoia saturate
    }
    return code | s;
}

__device__ __forceinline__ unsigned int pack_e4m3_4(float4 v) {
    return f2e4m3(v.x) | (f2e4m3(v.y) << 8) | (f2e4m3(v.z) << 16) | (f2e4m3(v.w) << 24);
}

// ---------------------------------------------------------------------------
// Kernel A: per-wave row normalize (structure validated r2-r4). Block=256
// (4 waves), wave w -> row i = blockIdx.x*4+w. float4 loads, shuffle
// reductions. Writes fp8 Xq=[a_n;b_n] (4 B/lane, coalesced), f32 SQ, and a
// unique-slot align partial (no atomics, no memset).
__global__ __launch_bounds__(256) void normalize_kernel(
        const float* __restrict__ A, const float* __restrict__ Bm,
        unsigned int* __restrict__ Xq, float* __restrict__ SQ,
        float* __restrict__ partials, int B_rows) {
    __shared__ float red[4];
    int lane = threadIdx.x & 63;
    int w    = threadIdx.x >> 6;
    int i    = blockIdx.x * 4 + w;

    const float4* A4 = (const float4*)(A + (size_t)i * D_DIM);
    const float4* B4 = (const float4*)(Bm + (size_t)i * D_DIM);
    float4 av = A4[lane];
    float4 bv = B4[lane];

    float sa = av.x*av.x + av.y*av.y + av.z*av.z + av.w*av.w;
    float sb = bv.x*bv.x + bv.y*bv.y + bv.z*bv.z + bv.w*bv.w;
    #pragma unroll
    for (int off = 32; off > 0; off >>= 1) {
        sa += __shfl_xor(sa, off, 64);
        sb += __shfl_xor(sb, off, 64);
    }
    float dena = fmaxf(sqrtf(sa), 1e-12f);
    float denb = fmaxf(sqrtf(sb), 1e-12f);
    float ia = 1.0f / dena, ib = 1.0f / denb;

    float4 an = {av.x*ia, av.y*ia, av.z*ia, av.w*ia};
    float4 bn = {bv.x*ib, bv.y*ib, bv.z*ib, bv.w*ib};

    // fp8 rows: 256 B each = 64 uints; lane writes uint at [row*64 + lane]
    Xq[(size_t)i * 64 + lane]            = pack_e4m3_4(an);
    Xq[(size_t)(B_rows + i) * 64 + lane] = pack_e4m3_4(bn);

    float dx = an.x-bn.x, dy = an.y-bn.y, dz = an.z-bn.z, dw = an.w-bn.w;
    float sd = dx*dx + dy*dy + dz*dz + dw*dw;
    #pragma unroll
    for (int off = 32; off > 0; off >>= 1) sd += __shfl_down(sd, off, 64);

    if (lane == 0) {
        SQ[i]          = sa * ia * ia;
        SQ[B_rows + i] = sb * ib * ib;
        red[w] = sd;
    }
    __syncthreads();
    if (threadIdx.x == 0)
        partials[blockIdx.x] = red[0]+red[1]+red[2]+red[3];
}

// ---------------------------------------------------------------------------
// Kernel B: uniformity via MX-fp8 MFMA Gram (m148-proven path: 2x bf16 MFMA
// rate + half staging bytes at the same 2-phase 128^2 structure). 4 waves
// (2x2, wave-tile 64x64), mfma_scale_f32_16x16x128_f8f6f4 with scale=1.0
// (E8M0 0x7F), fmt A/B = 0 (e4m3). BK=128 -> 2 K-steps. Both-sides XOR
// granule swizzle: linear LDS dest (global_load_lds 16B), inverse-swizzled
// global source, swizzled ds_read_b128 pairs (same 128-B-row geometry
// validated r2-r4). LDS padded -> 3 blocks/CU (2080/768 = 2.71 -> 90% sched).
__device__ __forceinline__ i32x4 lds_read16(const unsigned char* base, int r, int g) {
    int off = r * BKE + ((g ^ (r & 7)) << 4);
    return *reinterpret_cast<const i32x4*>(base + off);
}

__global__ __launch_bounds__(256, 3) void uniform_mfma_kernel(
        const unsigned char* __restrict__ Xq, const float* __restrict__ SQ,
        float* __restrict__ partials, int n_panels) {
    __shared__ __align__(16) unsigned char As[LDS_ALLOC];  // 16 KB used + pad
    __shared__ __align__(16) unsigned char Bs[LDS_ALLOC];
    __shared__ float sqa[TILE], sqb[TILE], red[4];

    int t    = threadIdx.x;
    int lane = t & 63;
    int w    = t >> 6;       // 0..3
    int wr   = w >> 1;       // A half: rows wr*64
    int wc   = w & 1;        // B half: rows wc*64

    // closed-form triangle decode: ib = smallest i with start(i+1) > bid,
    // start(i) = i*(2n-i+1)/2; float sqrt + +/-1 fixup.
    int bid = blockIdx.x;
    float nn = 2.0f * n_panels + 1.0f;
    int g = (int)((nn - sqrtf(nn * nn - 8.0f * (float)bid)) * 0.5f);
    #define TRI_START(i) (((i) * (2 * n_panels - (i) + 1)) >> 1)
    if (TRI_START(g + 1) <= bid) ++g;
    else if (TRI_START(g) > bid) --g;
    int ib = g;
    int jb = ib + (bid - TRI_START(ib));
    #undef TRI_START

    int rowA0 = ib * TILE, rowB0 = jb * TILE;
    if (t < TILE) sqa[t]        = SQ[rowA0 + t];
    else          sqb[t - TILE] = SQ[rowB0 + t - TILE];

    f32x4 acc[4][4] = {};

    for (int k0 = 0; k0 < D_DIM; k0 += BKE) {
        __syncthreads();   // prev-iter LDS reads done (covers sqa/sqb 1st iter)
        // STAGE: wave w stages rows [w*32, w*32+32) of both tiles.
        // Instruction 'it' fills 8 rows x 128 B = 1 KB linear LDS; lane ->
        // row +(l>>3), granule (l&7)^(row&7) inverse-swizzled at the source.
        #pragma unroll
        for (int it = 0; it < 4; ++it) {
            int row = w * 32 + it * 8 + (lane >> 3);
            int gsw = ((lane & 7) ^ (row & 7)) << 4;   // source byte offset
            const unsigned char* sA = Xq + (size_t)(rowA0 + row) * D_DIM + k0 + gsw;
            const unsigned char* sB = Xq + (size_t)(rowB0 + row) * D_DIM + k0 + gsw;
            unsigned char* dA = As + (w * 32 + it * 8) * BKE;
            unsigned char* dB = Bs + (w * 32 + it * 8) * BKE;
            __builtin_amdgcn_global_load_lds(AS_GLOBAL(sA), AS_LDS(dA), 16, 0, 0);
            __builtin_amdgcn_global_load_lds(AS_GLOBAL(sB), AS_LDS(dB), 16, 0, 0);
        }
        __syncthreads();   // staged data visible (compiler drains vmcnt)

        // COMPUTE: lane's k-chunk = (lane>>4)*32 elems -> granules 2q, 2q+1.
        int q  = lane >> 4;
        int g0 = q << 1;
        i32x8 a[4], b[4];
        #pragma unroll
        for (int m = 0; m < 4; ++m) {
            int r = wr * 64 + m * 16 + (lane & 15);
            i32x4 lo = lds_read16(As, r, g0);
            i32x4 hi = lds_read16(As, r, g0 + 1);
            a[m] = (i32x8){lo.x, lo.y, lo.z, lo.w, hi.x, hi.y, hi.z, hi.w};
        }
        #pragma unroll
        for (int n = 0; n < 4; ++n) {
            int r = wc * 64 + n * 16 + (lane & 15);
            i32x4 lo = lds_read16(Bs, r, g0);
            i32x4 hi = lds_read16(Bs, r, g0 + 1);
            b[n] = (i32x8){lo.x, lo.y, lo.z, lo.w, hi.x, hi.y, hi.z, hi.w};
        }
        #pragma unroll
        for (int m = 0; m < 4; ++m)
            #pragma unroll
            for (int n = 0; n < 4; ++n)
                acc[m][n] = __builtin_amdgcn_mfma_scale_f32_16x16x128_f8f6f4(
                    a[m], b[n], acc[m][n],
                    0, 0,                       // cbsz: A fmt fp8, blgp: B fmt fp8
                    0, 0x7f7f7f7f,              // opsel_a, scale_a (E8M0 1.0)
                    0, 0x7f7f7f7f);             // opsel_b, scale_b
    }

    // Epilogue: e = exp(-2 * max(sq_i + sq_j - 2*dot, 0)), reduce.
    // C layout (16x16, shape-determined): col = lane&15, row = (lane>>4)*4+reg
    float s   = 0.0f;
    int   col = lane & 15;
    int   rhi = (lane >> 4) * 4;
    #pragma unroll
    for (int m = 0; m < 4; ++m)
        #pragma unroll
        for (int n = 0; n < 4; ++n)
            #pragma unroll
            for (int reg = 0; reg < 4; ++reg) {
                int il = wr * 64 + m * 16 + rhi + reg;
                int jl = wc * 64 + n * 16 + col;
                float d2 = fmaxf(sqa[il] + sqb[jl] - 2.0f * acc[m][n][reg], 0.0f);
                s += __expf(-2.0f * d2);
            }
    if (ib != jb) s *= 2.0f;

    #pragma unroll
    for (int off = 32; off > 0; off >>= 1) s += __shfl_down(s, off, 64);
    if (lane == 0) red[w] = s;
    __syncthreads();
    if (t == 0)
        partials[1024 + blockIdx.x] = red[0]+red[1]+red[2]+red[3];  // unique slot
}

// ---------------------------------------------------------------------------
// Finalize: sum 1024 align partials + n_blocks uniform partials, one block.
__global__ __launch_bounds__(256) void finalize_kernel(
        const float* __restrict__ partials, float* __restrict__ out,
        int B_rows, int n_blocks) {
    __shared__ float reda[4], redu[4];
    int t = threadIdx.x;
    float al = 0.0f, un = 0.0f;
    for (int i = t; i < 1024; i += 256)      al += partials[i];
    for (int i = t; i < n_blocks; i += 256)  un += partials[1024 + i];
    #pragma unroll
    for (int off = 32; off > 0; off >>= 1) {
        al += __shfl_down(al, off, 64);
        un += __shfl_down(un, off, 64);
    }
    if ((t & 63) == 0) { reda[t >> 6] = al; redu[t >> 6] = un; }
    __syncthreads();
    if (t == 0) {
        float sal = reda[0]+reda[1]+reda[2]+reda[3];
        float sun = redu[0]+redu[1]+redu[2]+redu[3];
        float n = (float)(2 * B_rows);
        out[0] = sal / (float)B_rows + (sun - n) / (n * (n - 1.0f));
    }
}

// ---------------------------------------------------------------------------
extern "C" void kernel_launch(void* const* d_in, const int* in_sizes, int n_in,
                              void* d_out, int out_size, void* d_ws, size_t ws_size,
                              hipStream_t stream) {
    const float* A  = (const float*)d_in[0];
    const float* Bm = (const float*)d_in[1];
    float* out = (float*)d_out;

    int B_rows = in_sizes[0] / D_DIM;   // 4096
    int n_tot  = 2 * B_rows;            // 8192

    // ws layout: Xq (fp8 n*256 = 2 MB) | SQ (f32 n) | partials (f32 1024+2080)
    unsigned char* Xq = (unsigned char*)d_ws;
    float* SQ       = (float*)(Xq + (size_t)n_tot * D_DIM);
    float* partials = SQ + n_tot;

    normalize_kernel<<<B_rows / 4, 256, 0, stream>>>(A, Bm, (unsigned int*)Xq,
                                                     SQ, partials, B_rows);

    int n_panels = n_tot / TILE;                    // 64
    int n_blocks = n_panels * (n_panels + 1) / 2;   // 2080
    uniform_mfma_kernel<<<n_blocks, 256, 0, stream>>>(Xq, SQ, partials, n_panels);

    finalize_kernel<<<1, 256, 0, stream>>>(partials, out, B_rows, n_blocks);
}